// Round 5
// baseline (333.145 us; speedup 1.0000x reference)
//
#include <hip/hip_runtime.h>

#define NND 20000
#define NE 200000
#define PDROP 0.1f

typedef unsigned short u16;
typedef __bf16 bf16x8 __attribute__((ext_vector_type(8)));
typedef float f32x4 __attribute__((ext_vector_type(4)));

__device__ __forceinline__ float b2f(u16 u) {
  unsigned v = ((unsigned)u) << 16;
  float f;
  __builtin_memcpy(&f, &v, 4);
  return f;
}
__device__ __forceinline__ u16 f2b(float f) {
  unsigned x;
  __builtin_memcpy(&x, &f, 4);
  unsigned r = x + 0x7fffu + ((x >> 16) & 1u);
  return (u16)(r >> 16);
}

__global__ void convert_x(const float* __restrict__ x, u16* __restrict__ xb) {
  int i = blockIdx.x * blockDim.x + threadIdx.x;
  if (i < NND * 256 / 4) {
    float4 v = ((const float4*)x)[i];
    ushort4 o;
    o.x = f2b(v.x); o.y = f2b(v.y); o.z = f2b(v.z); o.w = f2b(v.w);
    ((ushort4*)xb)[i] = o;
  }
}

// 0..3: Wq,Wk,Wv,Ws transposed; 4: We transposed (WeT); 5: We row-major (Web)
struct WTArgs {
  const float* W[6];
  u16* WT[6];
};
__global__ void convert_wT(WTArgs a) {
  int gid = blockIdx.x * blockDim.x + threadIdx.x;
  if (gid >= 6 * 65536) return;
  int w = gid >> 16, r = gid & 65535;
  if (w < 5) {
    int n = r >> 8, k = r & 255;
    a.WT[w][n * 256 + k] = f2b(a.W[w][k * 256 + n]);
  } else {
    a.WT[5][r] = f2b(a.W[5][r]);
  }
}

// ---- CSR build over dst (with inverse permutation pos[e] = slot) ----
__global__ void zero2(int* __restrict__ cnt, int* __restrict__ cur) {
  int i = blockIdx.x * blockDim.x + threadIdx.x;
  if (i < NND) { cnt[i] = 0; cur[i] = 0; }
}
__global__ void csr_count(const int* __restrict__ ei, int* __restrict__ cnt) {
  int e = blockIdx.x * blockDim.x + threadIdx.x;
  if (e < NE) atomicAdd(&cnt[ei[NE + e]], 1);
}
__global__ __launch_bounds__(1024) void scan_rowptr(const int* __restrict__ cnt,
                                                    int* __restrict__ rowptr) {
  __shared__ int sums[1024];
  const int tid = threadIdx.x;
  const int base = tid * 20;
  int local[20];
  int run = 0;
#pragma unroll
  for (int i = 0; i < 20; i++) {
    int idx = base + i;
    local[i] = run;
    run += (idx < NND) ? cnt[idx] : 0;
  }
  sums[tid] = run;
  __syncthreads();
  for (int off = 1; off < 1024; off <<= 1) {
    int v = (tid >= off) ? sums[tid - off] : 0;
    __syncthreads();
    sums[tid] += v;
    __syncthreads();
  }
  int prev = (tid > 0) ? sums[tid - 1] : 0;
#pragma unroll
  for (int i = 0; i < 20; i++) {
    int idx = base + i;
    if (idx < NND) rowptr[idx] = prev + local[i];
  }
  if (tid == 1023) rowptr[NND] = sums[1023];
}
__global__ void csr_fill(const int* __restrict__ ei, const int* __restrict__ rowptr,
                         int* __restrict__ cur, int* __restrict__ elist,
                         int* __restrict__ pos) {
  int e = blockIdx.x * blockDim.x + threadIdx.x;
  if (e < NE) {
    int d = ei[NE + e];
    int p = rowptr[d] + atomicAdd(&cur[d], 1);
    elist[p] = e;
    pos[e] = p;
  }
}

// ---- shared MFMA compute: 4 waves, each 64x64 of a 128x128 tile ----
__device__ __forceinline__ void mfma_tile(const u16 (*As)[72], const u16 (*Bs)[72],
                                          f32x4 acc[4][4], int wm, int wn,
                                          int fr, int fg) {
#pragma unroll
  for (int ks = 0; ks < 2; ks++) {
    bf16x8 a[4], b[4];
#pragma unroll
    for (int i = 0; i < 4; i++)
      a[i] = *(const bf16x8*)&As[wm * 64 + i * 16 + fr][ks * 32 + fg * 8];
#pragma unroll
    for (int j = 0; j < 4; j++)
      b[j] = *(const bf16x8*)&Bs[wn * 64 + j * 16 + fr][ks * 32 + fg * 8];
#pragma unroll
    for (int i = 0; i < 4; i++)
#pragma unroll
      for (int j = 0; j < 4; j++)
        acc[i][j] = __builtin_amdgcn_mfma_f32_16x16x32_bf16(a[i], b[j], acc[i][j], 0, 0, 0);
  }
}

// ---- fused node GEMM: y in [0,8): w=y>>1 selects {Wq,Wk,Wv,Ws} ----
struct NodeArgs {
  const u16* BT[4];
  const float* bias[4];
  u16* outb[3];   // q, k, v (bf16)
  float* outf;    // skip -> d_out (f32)
};
__global__ __launch_bounds__(256) void gemm_node(const u16* __restrict__ xb,
                                                 NodeArgs args) {
  __shared__ __attribute__((aligned(16))) u16 As[128][72];
  __shared__ __attribute__((aligned(16))) u16 Bs[128][72];
  const int tid = threadIdx.x;
  const int w = blockIdx.y >> 1;
  const int col0 = (blockIdx.y & 1) * 128;
  const int row0 = blockIdx.x * 128;
  const u16* BT = args.BT[w];
  const float* bias = args.bias[w];
  const int wid = tid >> 6, lane = tid & 63;
  const int wm = wid >> 1, wn = wid & 1;
  const int fr = lane & 15, fg = lane >> 4;
  f32x4 acc[4][4] = {};
  for (int k0 = 0; k0 < 256; k0 += 64) {
#pragma unroll
    for (int i = 0; i < 4; i++) {
      int idx = tid + i * 256;
      int row = idx >> 3, vc = idx & 7;
      int g = row0 + row;
      uint4 v = make_uint4(0, 0, 0, 0);
      if (g < NND) v = *(const uint4*)&xb[(size_t)g * 256 + k0 + vc * 8];
      *(uint4*)&As[row][vc * 8] = v;
      *(uint4*)&Bs[row][vc * 8] = *(const uint4*)&BT[(size_t)(col0 + row) * 256 + k0 + vc * 8];
    }
    __syncthreads();
    mfma_tile(As, Bs, acc, wm, wn, fr, fg);
    __syncthreads();
  }
#pragma unroll
  for (int mi = 0; mi < 4; mi++) {
#pragma unroll
    for (int rr = 0; rr < 4; rr++) {
      int grow = row0 + wm * 64 + mi * 16 + fg * 4 + rr;
      if (grow >= NND) continue;
#pragma unroll
      for (int ni = 0; ni < 4; ni++) {
        int gcol = col0 + wn * 64 + ni * 16 + fr;
        float val = acc[mi][ni][rr] + bias[gcol];
        if (w < 3)
          args.outb[w][(size_t)grow * 256 + gcol] = f2b(val);
        else
          args.outf[(size_t)grow * 256 + gcol] = val;
      }
    }
  }
}

// ---- qWe GEMM: qWe[n,h,j] = sum_c We[j, h*128+c] * q[n, h*128+c] ----
__global__ __launch_bounds__(256) void gemm_qwe(const u16* __restrict__ qb,
                                                const u16* __restrict__ Web,
                                                u16* __restrict__ qWeb) {
  __shared__ __attribute__((aligned(16))) u16 As[128][72];
  __shared__ __attribute__((aligned(16))) u16 Bs[128][72];
  const int tid = threadIdx.x;
  const int h = blockIdx.y >> 1;
  const int col0 = (blockIdx.y & 1) * 128;
  const int row0 = blockIdx.x * 128;
  const int wid = tid >> 6, lane = tid & 63;
  const int wm = wid >> 1, wn = wid & 1;
  const int fr = lane & 15, fg = lane >> 4;
  f32x4 acc[4][4] = {};
  for (int k0 = 0; k0 < 128; k0 += 64) {
#pragma unroll
    for (int i = 0; i < 4; i++) {
      int idx = tid + i * 256;
      int row = idx >> 3, vc = idx & 7;
      int g = row0 + row;
      uint4 v = make_uint4(0, 0, 0, 0);
      if (g < NND) v = *(const uint4*)&qb[(size_t)g * 256 + h * 128 + k0 + vc * 8];
      *(uint4*)&As[row][vc * 8] = v;
      *(uint4*)&Bs[row][vc * 8] =
          *(const uint4*)&Web[(size_t)(col0 + row) * 256 + h * 128 + k0 + vc * 8];
    }
    __syncthreads();
    mfma_tile(As, Bs, acc, wm, wn, fr, fg);
    __syncthreads();
  }
#pragma unroll
  for (int mi = 0; mi < 4; mi++) {
#pragma unroll
    for (int rr = 0; rr < 4; rr++) {
      int grow = row0 + wm * 64 + mi * 16 + fg * 4 + rr;
      if (grow >= NND) continue;
#pragma unroll
      for (int ni = 0; ni < 4; ni++) {
        int gj = col0 + wn * 64 + ni * 16 + fr;
        qWeb[(size_t)grow * 512 + h * 256 + gj] = f2b(acc[mi][ni][rr]);
      }
    }
  }
}

// ---- edge-parallel alpha: wave per edge, original edge order ----
// writes (CSR-slot indexed): alpha2, wm2, reltc, srcc; and msgb (edge order)
__global__ __launch_bounds__(256) void edge_alpha(
    const u16* __restrict__ qb, const u16* __restrict__ kb,
    const u16* __restrict__ qWeb, const int* __restrict__ ei,
    const float* __restrict__ last_update, const float* __restrict__ t,
    const float* __restrict__ msg, const float* __restrict__ tw,
    const float* __restrict__ tb_, const float* __restrict__ be,
    const float* __restrict__ u_edge, const float* __restrict__ u_attn,
    const int* __restrict__ pos, float2* __restrict__ alpha2,
    float2* __restrict__ wm2, float* __restrict__ reltc,
    int* __restrict__ srcc, u16* __restrict__ msgb) {
  int e = (blockIdx.x * blockDim.x + threadIdx.x) >> 6;
  int lane = threadIdx.x & 63;
  if (e >= NE) return;
  int c0 = lane * 4;
  int s = ei[e], d = ei[NE + e];
  float rt = last_update[s] - t[e];
  ushort4 q4 = *(const ushort4*)&qb[(size_t)d * 256 + c0];
  ushort4 k4 = *(const ushort4*)&kb[(size_t)s * 256 + c0];
  float4 bev = *(const float4*)&be[c0];
  // q·(k+be) — per-head after 32-lane fold
  float pqk = b2f(q4.x) * (b2f(k4.x) + bev.x) + b2f(q4.y) * (b2f(k4.y) + bev.y) +
              b2f(q4.z) * (b2f(k4.z) + bev.z) + b2f(q4.w) * (b2f(k4.w) + bev.w);
  // edge_attr chunk for this lane
  float ea0, ea1, ea2, ea3;
  if (c0 < 100) {
    float4 a = *(const float4*)&tw[c0];
    float4 b = *(const float4*)&tb_[c0];
    ea0 = __cosf(rt * a.x + b.x); ea1 = __cosf(rt * a.y + b.y);
    ea2 = __cosf(rt * a.z + b.z); ea3 = __cosf(rt * a.w + b.w);
  } else {
    float4 mm = *(const float4*)&msg[(size_t)e * 156 + (c0 - 100)];
    ea0 = mm.x; ea1 = mm.y; ea2 = mm.z; ea3 = mm.w;
    ushort4 mo;
    mo.x = f2b(ea0); mo.y = f2b(ea1); mo.z = f2b(ea2); mo.w = f2b(ea3);
    *(ushort4*)&msgb[(size_t)e * 156 + (c0 - 100)] = mo;
  }
  ushort4 w0v = *(const ushort4*)&qWeb[(size_t)d * 512 + c0];
  ushort4 w1v = *(const ushort4*)&qWeb[(size_t)d * 512 + 256 + c0];
  float pe0 = b2f(w0v.x) * ea0 + b2f(w0v.y) * ea1 + b2f(w0v.z) * ea2 + b2f(w0v.w) * ea3;
  float pe1 = b2f(w1v.x) * ea0 + b2f(w1v.y) * ea1 + b2f(w1v.z) * ea2 + b2f(w1v.w) * ea3;
  float y0 = pe0 + __shfl_xor(pe0, 32);
  float y1 = pe1 + __shfl_xor(pe1, 32);
  float z = (lane < 32) ? y0 : y1;
#pragma unroll
  for (int off = 16; off; off >>= 1) {
    z += __shfl_xor(z, off);
    pqk += __shfl_xor(pqk, off);
  }
  float a = (pqk + z) * 0.08838834764831845f;  // 1/sqrt(128)
  if (!(u_edge[e] > PDROP)) a = -INFINITY;
  float aothr = __shfl_xor(a, 32);
  if (lane == 0) {
    int p = pos[e];
    alpha2[p] = make_float2(a, aothr);
    float2 ua = *(const float2*)&u_attn[(size_t)e * 2];
    wm2[p] = make_float2(ua.x > PDROP ? (1.f / 0.9f) : 0.f,
                         ua.y > PDROP ? (1.f / 0.9f) : 0.f);
    reltc[p] = rt;
    srcc[p] = s;
  }
}

// ---- per-node aggregation: no cross-lane ops at all ----
__global__ __launch_bounds__(256) void node_agg(
    const u16* __restrict__ vb, const u16* __restrict__ msgb,
    const float2* __restrict__ alpha2, const float2* __restrict__ wm2,
    const float* __restrict__ reltc, const int* __restrict__ srcc,
    const int* __restrict__ elist, const int* __restrict__ rowptr,
    const float* __restrict__ tw, const float* __restrict__ tb_,
    const float* __restrict__ be, u16* __restrict__ aggb,
    float* __restrict__ out) {
  int node = (blockIdx.x * blockDim.x + threadIdx.x) >> 6;
  int lane = threadIdx.x & 63;
  if (node >= NND) return;
  const int beg = rowptr[node], end = rowptr[node + 1];
  const int c0 = lane * 4, hl = lane >> 5;
  float tw0 = 0, tw1 = 0, tw2 = 0, tw3 = 0, tb0 = 0, tb1 = 0, tb2 = 0, tb3 = 0;
  if (c0 < 100) {
    float4 a = *(const float4*)&tw[c0];
    float4 b = *(const float4*)&tb_[c0];
    tw0 = a.x; tw1 = a.y; tw2 = a.z; tw3 = a.w;
    tb0 = b.x; tb1 = b.y; tb2 = b.z; tb3 = b.w;
  }
  float4 bev = *(const float4*)&be[c0];
  // pass A: per-head maxima (redundant per lane, no shfl)
  float m0 = -INFINITY, m1 = -INFINITY;
  for (int j = beg; j < end; ++j) {
    float2 a2 = alpha2[j];
    m0 = fmaxf(m0, a2.x);
    m1 = fmaxf(m1, a2.y);
  }
  // pass B: denom + weighted accumulation
  float den0 = 0.f, den1 = 0.f, sw0 = 0.f, sw1 = 0.f;
  float vc0 = 0, vc1 = 0, vc2 = 0, vc3 = 0;
  float g00 = 0, g01 = 0, g02 = 0, g03 = 0;
  float g10 = 0, g11 = 0, g12 = 0, g13 = 0;
  for (int j = beg; j < end; ++j) {
    float2 a2 = alpha2[j];
    float ex0 = (a2.x > -1e30f) ? __expf(a2.x - m0) : 0.f;
    float ex1 = (a2.y > -1e30f) ? __expf(a2.y - m1) : 0.f;
    den0 += ex0; den1 += ex1;
    float2 wm = wm2[j];
    float w0 = ex0 * wm.x, w1 = ex1 * wm.y;
    if (w0 + w1 != 0.f) {  // wave-uniform
      int s = srcc[j];
      float rt = reltc[j];
      ushort4 v4 = *(const ushort4*)&vb[(size_t)s * 256 + c0];
      float ea0, ea1, ea2, ea3;
      if (c0 < 100) {
        ea0 = __cosf(rt * tw0 + tb0); ea1 = __cosf(rt * tw1 + tb1);
        ea2 = __cosf(rt * tw2 + tb2); ea3 = __cosf(rt * tw3 + tb3);
      } else {
        int eid = elist[j];
        ushort4 mm = *(const ushort4*)&msgb[(size_t)eid * 156 + (c0 - 100)];
        ea0 = b2f(mm.x); ea1 = b2f(mm.y); ea2 = b2f(mm.z); ea3 = b2f(mm.w);
      }
      float wv = hl ? w1 : w0;
      vc0 += wv * b2f(v4.x); vc1 += wv * b2f(v4.y);
      vc2 += wv * b2f(v4.z); vc3 += wv * b2f(v4.w);
      g00 += w0 * ea0; g01 += w0 * ea1; g02 += w0 * ea2; g03 += w0 * ea3;
      g10 += w1 * ea0; g11 += w1 * ea1; g12 += w1 * ea2; g13 += w1 * ea3;
      sw0 += w0; sw1 += w1;
    }
  }
  float rden0 = 1.f / (den0 + 1e-16f), rden1 = 1.f / (den1 + 1e-16f);
  float rv = hl ? rden1 : rden0;
  float swv = hl ? sw1 : sw0;
  float4 o = *(float4*)&out[(size_t)node * 256 + c0];
  o.x += (vc0 + swv * bev.x) * rv;
  o.y += (vc1 + swv * bev.y) * rv;
  o.z += (vc2 + swv * bev.z) * rv;
  o.w += (vc3 + swv * bev.w) * rv;
  *(float4*)&out[(size_t)node * 256 + c0] = o;
  ushort4 a0, a1;
  a0.x = f2b(g00 * rden0); a0.y = f2b(g01 * rden0);
  a0.z = f2b(g02 * rden0); a0.w = f2b(g03 * rden0);
  a1.x = f2b(g10 * rden1); a1.y = f2b(g11 * rden1);
  a1.z = f2b(g12 * rden1); a1.w = f2b(g13 * rden1);
  *(ushort4*)&aggb[(size_t)node * 256 + c0] = a0;
  *(ushort4*)&aggb[(size_t)(NND + node) * 256 + c0] = a1;
}

// ---- final GEMM: out[:, h*128 + c] += agg_h (Nx256) @ We_h (256x128) ----
__global__ __launch_bounds__(256) void gemm_final(const u16* __restrict__ aggb,
                                                  const u16* __restrict__ WeT,
                                                  float* __restrict__ out) {
  __shared__ __attribute__((aligned(16))) u16 As[128][72];
  __shared__ __attribute__((aligned(16))) u16 Bs[128][72];
  const int tid = threadIdx.x;
  const int h = blockIdx.y;
  const int row0 = blockIdx.x * 128;
  const u16* A = aggb + (size_t)h * NND * 256;
  const int wid = tid >> 6, lane = tid & 63;
  const int wm = wid >> 1, wn = wid & 1;
  const int fr = lane & 15, fg = lane >> 4;
  f32x4 acc[4][4] = {};
  for (int k0 = 0; k0 < 256; k0 += 64) {
#pragma unroll
    for (int i = 0; i < 4; i++) {
      int idx = tid + i * 256;
      int row = idx >> 3, vc = idx & 7;
      int g = row0 + row;
      uint4 v = make_uint4(0, 0, 0, 0);
      if (g < NND) v = *(const uint4*)&A[(size_t)g * 256 + k0 + vc * 8];
      *(uint4*)&As[row][vc * 8] = v;
      *(uint4*)&Bs[row][vc * 8] =
          *(const uint4*)&WeT[(size_t)(h * 128 + row) * 256 + k0 + vc * 8];
    }
    __syncthreads();
    mfma_tile(As, Bs, acc, wm, wn, fr, fg);
    __syncthreads();
  }
#pragma unroll
  for (int mi = 0; mi < 4; mi++) {
#pragma unroll
    for (int rr = 0; rr < 4; rr++) {
      int grow = row0 + wm * 64 + mi * 16 + fg * 4 + rr;
      if (grow >= NND) continue;
#pragma unroll
      for (int ni = 0; ni < 4; ni++) {
        int gcol = wn * 64 + ni * 16 + fr;
        out[(size_t)grow * 256 + h * 128 + gcol] += acc[mi][ni][rr];
      }
    }
  }
}

extern "C" void kernel_launch(void* const* d_in, const int* in_sizes, int n_in,
                              void* d_out, int out_size, void* d_ws, size_t ws_size,
                              hipStream_t stream) {
  const float* x = (const float*)d_in[0];
  const float* last_update = (const float*)d_in[1];
  const int* ei = (const int*)d_in[2];
  const float* t = (const float*)d_in[3];
  const float* msg = (const float*)d_in[4];
  const float* u_edge = (const float*)d_in[5];
  const float* u_attn = (const float*)d_in[6];
  const float* time_w = (const float*)d_in[7];
  const float* time_b = (const float*)d_in[8];
  const float* Wq = (const float*)d_in[9];
  const float* bq = (const float*)d_in[10];
  const float* Wk = (const float*)d_in[11];
  const float* bk = (const float*)d_in[12];
  const float* Wv = (const float*)d_in[13];
  const float* bv = (const float*)d_in[14];
  const float* We = (const float*)d_in[15];
  const float* be = (const float*)d_in[16];
  const float* Ws = (const float*)d_in[17];
  const float* bs = (const float*)d_in[18];
  float* out = (float*)d_out;

  char* ws = (char*)d_ws;
  u16* xb = (u16*)(ws + 0);                    // 10,240,000
  u16* WT0 = (u16*)(ws + 10240000);            // 786,432
  u16* qb = (u16*)(ws + 11026432);             // 10,240,000
  u16* kb = (u16*)(ws + 21266432);             // 10,240,000
  u16* vb = (u16*)(ws + 31506432);             // 10,240,000
  u16* qWeb = (u16*)(ws + 41746432);           // 20,480,000
  u16* aggb = (u16*)(ws + 62226432);           // 20,480,000
  float2* alpha2 = (float2*)(ws + 82706432);   // 1,600,000
  float2* wm2 = (float2*)(ws + 84306432);      // 1,600,000
  float* reltc = (float*)(ws + 85906432);      // 800,000
  int* srcc = (int*)(ws + 86706432);           // 800,000
  int* pos = (int*)(ws + 87506432);            // 800,000
  int* elist = (int*)(ws + 88306432);          // 800,000
  u16* msgb = (u16*)(ws + 89106432);           // 62,400,000
  int* cnt = (int*)(ws + 151506432);           // 80,000
  int* cur = (int*)(ws + 151586432);           // 80,000
  int* rowptr = (int*)(ws + 151666432);        // 80,016
  // total ~151.7 MB

  // CSR build
  zero2<<<(NND + 255) / 256, 256, 0, stream>>>(cnt, cur);
  csr_count<<<(NE + 255) / 256, 256, 0, stream>>>(ei, cnt);
  scan_rowptr<<<1, 1024, 0, stream>>>(cnt, rowptr);
  csr_fill<<<(NE + 255) / 256, 256, 0, stream>>>(ei, rowptr, cur, elist, pos);

  // precompute
  WTArgs wa;
  wa.W[0] = Wq; wa.W[1] = Wk; wa.W[2] = Wv; wa.W[3] = Ws; wa.W[4] = We; wa.W[5] = We;
  for (int i = 0; i < 6; i++) wa.WT[i] = WT0 + (size_t)i * 65536;
  convert_wT<<<(6 * 65536 + 255) / 256, 256, 0, stream>>>(wa);
  convert_x<<<(NND * 64 + 255) / 256, 256, 0, stream>>>(x, xb);

  // node projections (q,k,v bf16; skip f32 -> out)
  NodeArgs na;
  na.BT[0] = wa.WT[0]; na.BT[1] = wa.WT[1]; na.BT[2] = wa.WT[2]; na.BT[3] = wa.WT[3];
  na.bias[0] = bq; na.bias[1] = bk; na.bias[2] = bv; na.bias[3] = bs;
  na.outb[0] = qb; na.outb[1] = kb; na.outb[2] = vb;
  na.outf = out;
  dim3 gn((NND + 127) / 128, 8);
  gemm_node<<<gn, 256, 0, stream>>>(xb, na);

  // qWe[n,h,256]
  dim3 gq((NND + 127) / 128, 4);
  gemm_qwe<<<gq, 256, 0, stream>>>(qb, wa.WT[5], qWeb);

  // edge-parallel alpha (+ bf16 msg cache)
  edge_alpha<<<(NE + 3) / 4, 256, 0, stream>>>(
      qb, kb, qWeb, ei, last_update, t, msg, time_w, time_b, be, u_edge,
      u_attn, pos, alpha2, wm2, reltc, srcc, msgb);

  // per-node softmax + aggregation
  node_agg<<<(NND + 3) / 4, 256, 0, stream>>>(
      vb, msgb, alpha2, wm2, reltc, srcc, elist, rowptr, time_w, time_b, be,
      aggb, out);

  // out += agg_h @ We_h
  dim3 gf((NND + 127) / 128, 2);
  gemm_final<<<gf, 256, 0, stream>>>(aggb, wa.WT[4], out);
}

// Round 6
// 238.409 us; speedup vs baseline: 1.3974x; 1.3974x over previous
//
#include <hip/hip_runtime.h>

#define NND 20000
#define NE 200000
#define PDROP 0.1f

typedef unsigned short u16;
typedef __bf16 bf16x8 __attribute__((ext_vector_type(8)));
typedef float f32x4 __attribute__((ext_vector_type(4)));

__device__ __forceinline__ float b2f(u16 u) {
  unsigned v = ((unsigned)u) << 16;
  float f;
  __builtin_memcpy(&f, &v, 4);
  return f;
}
__device__ __forceinline__ u16 f2b(float f) {
  unsigned x;
  __builtin_memcpy(&x, &f, 4);
  unsigned r = x + 0x7fffu + ((x >> 16) & 1u);
  return (u16)(r >> 16);
}

__global__ void convert_x(const float* __restrict__ x, u16* __restrict__ xb) {
  int i = blockIdx.x * blockDim.x + threadIdx.x;
  if (i < NND * 256 / 4) {
    float4 v = ((const float4*)x)[i];
    ushort4 o;
    o.x = f2b(v.x); o.y = f2b(v.y); o.z = f2b(v.z); o.w = f2b(v.w);
    ((ushort4*)xb)[i] = o;
  }
}

// 0..3: Wq,Wk,Wv,Ws transposed; 4: We transposed (WeT); 5: We row-major (Web)
struct WTArgs {
  const float* W[6];
  u16* WT[6];
};
__global__ void convert_wT(WTArgs a) {
  int gid = blockIdx.x * blockDim.x + threadIdx.x;
  if (gid >= 6 * 65536) return;
  int w = gid >> 16, r = gid & 65535;
  if (w < 5) {
    int n = r >> 8, k = r & 255;
    a.WT[w][n * 256 + k] = f2b(a.W[w][k * 256 + n]);
  } else {
    a.WT[5][r] = f2b(a.W[5][r]);
  }
}

// ---- CSR build over dst ----
__global__ void zero2(int* __restrict__ cnt, int* __restrict__ cur) {
  int i = blockIdx.x * blockDim.x + threadIdx.x;
  if (i < NND) { cnt[i] = 0; cur[i] = 0; }
}
__global__ void csr_count(const int* __restrict__ ei, int* __restrict__ cnt) {
  int e = blockIdx.x * blockDim.x + threadIdx.x;
  if (e < NE) atomicAdd(&cnt[ei[NE + e]], 1);
}
__global__ __launch_bounds__(1024) void scan_rowptr(const int* __restrict__ cnt,
                                                    int* __restrict__ rowptr) {
  __shared__ int sums[1024];
  const int tid = threadIdx.x;
  const int base = tid * 20;
  int local[20];
  int run = 0;
#pragma unroll
  for (int i = 0; i < 20; i++) {
    int idx = base + i;
    local[i] = run;
    run += (idx < NND) ? cnt[idx] : 0;
  }
  sums[tid] = run;
  __syncthreads();
  for (int off = 1; off < 1024; off <<= 1) {
    int v = (tid >= off) ? sums[tid - off] : 0;
    __syncthreads();
    sums[tid] += v;
    __syncthreads();
  }
  int prev = (tid > 0) ? sums[tid - 1] : 0;
#pragma unroll
  for (int i = 0; i < 20; i++) {
    int idx = base + i;
    if (idx < NND) rowptr[idx] = prev + local[i];
  }
  if (tid == 1023) rowptr[NND] = sums[1023];
}
__global__ void csr_fill(const int* __restrict__ ei, const int* __restrict__ rowptr,
                         int* __restrict__ cur, int* __restrict__ elist) {
  int e = blockIdx.x * blockDim.x + threadIdx.x;
  if (e < NE) {
    int d = ei[NE + e];
    int p = rowptr[d] + atomicAdd(&cur[d], 1);
    elist[p] = e;
  }
}

// ---- shared MFMA compute: 4 waves, each 64x64 of a 128x128 tile ----
__device__ __forceinline__ void mfma_tile(const u16 (*As)[72], const u16 (*Bs)[72],
                                          f32x4 acc[4][4], int wm, int wn,
                                          int fr, int fg) {
#pragma unroll
  for (int ks = 0; ks < 2; ks++) {
    bf16x8 a[4], b[4];
#pragma unroll
    for (int i = 0; i < 4; i++)
      a[i] = *(const bf16x8*)&As[wm * 64 + i * 16 + fr][ks * 32 + fg * 8];
#pragma unroll
    for (int j = 0; j < 4; j++)
      b[j] = *(const bf16x8*)&Bs[wn * 64 + j * 16 + fr][ks * 32 + fg * 8];
#pragma unroll
    for (int i = 0; i < 4; i++)
#pragma unroll
      for (int j = 0; j < 4; j++)
        acc[i][j] = __builtin_amdgcn_mfma_f32_16x16x32_bf16(a[i], b[j], acc[i][j], 0, 0, 0);
  }
}

// ---- fused node GEMM: y in [0,8): w=y>>1 selects {Wq,Wk,Wv,Ws} ----
struct NodeArgs {
  const u16* BT[4];
  const float* bias[4];
  u16* outb[3];   // q, k, v (bf16)
  float* outf;    // skip -> d_out (f32)
};
__global__ __launch_bounds__(256) void gemm_node(const u16* __restrict__ xb,
                                                 NodeArgs args) {
  __shared__ __attribute__((aligned(16))) u16 As[128][72];
  __shared__ __attribute__((aligned(16))) u16 Bs[128][72];
  const int tid = threadIdx.x;
  const int w = blockIdx.y >> 1;
  const int col0 = (blockIdx.y & 1) * 128;
  const int row0 = blockIdx.x * 128;
  const u16* BT = args.BT[w];
  const float* bias = args.bias[w];
  const int wid = tid >> 6, lane = tid & 63;
  const int wm = wid >> 1, wn = wid & 1;
  const int fr = lane & 15, fg = lane >> 4;
  f32x4 acc[4][4] = {};
  for (int k0 = 0; k0 < 256; k0 += 64) {
#pragma unroll
    for (int i = 0; i < 4; i++) {
      int idx = tid + i * 256;
      int row = idx >> 3, vc = idx & 7;
      int g = row0 + row;
      uint4 v = make_uint4(0, 0, 0, 0);
      if (g < NND) v = *(const uint4*)&xb[(size_t)g * 256 + k0 + vc * 8];
      *(uint4*)&As[row][vc * 8] = v;
      *(uint4*)&Bs[row][vc * 8] = *(const uint4*)&BT[(size_t)(col0 + row) * 256 + k0 + vc * 8];
    }
    __syncthreads();
    mfma_tile(As, Bs, acc, wm, wn, fr, fg);
    __syncthreads();
  }
#pragma unroll
  for (int mi = 0; mi < 4; mi++) {
#pragma unroll
    for (int rr = 0; rr < 4; rr++) {
      int grow = row0 + wm * 64 + mi * 16 + fg * 4 + rr;
      if (grow >= NND) continue;
#pragma unroll
      for (int ni = 0; ni < 4; ni++) {
        int gcol = col0 + wn * 64 + ni * 16 + fr;
        float val = acc[mi][ni][rr] + bias[gcol];
        if (w < 3)
          args.outb[w][(size_t)grow * 256 + gcol] = f2b(val);
        else
          args.outf[(size_t)grow * 256 + gcol] = val;
      }
    }
  }
}

// ---- qWe GEMM: qWe[n,h,j] = sum_c We[j, h*128+c] * q[n, h*128+c] ----
__global__ __launch_bounds__(256) void gemm_qwe(const u16* __restrict__ qb,
                                                const u16* __restrict__ Web,
                                                u16* __restrict__ qWeb) {
  __shared__ __attribute__((aligned(16))) u16 As[128][72];
  __shared__ __attribute__((aligned(16))) u16 Bs[128][72];
  const int tid = threadIdx.x;
  const int h = blockIdx.y >> 1;
  const int col0 = (blockIdx.y & 1) * 128;
  const int row0 = blockIdx.x * 128;
  const int wid = tid >> 6, lane = tid & 63;
  const int wm = wid >> 1, wn = wid & 1;
  const int fr = lane & 15, fg = lane >> 4;
  f32x4 acc[4][4] = {};
  for (int k0 = 0; k0 < 128; k0 += 64) {
#pragma unroll
    for (int i = 0; i < 4; i++) {
      int idx = tid + i * 256;
      int row = idx >> 3, vc = idx & 7;
      int g = row0 + row;
      uint4 v = make_uint4(0, 0, 0, 0);
      if (g < NND) v = *(const uint4*)&qb[(size_t)g * 256 + h * 128 + k0 + vc * 8];
      *(uint4*)&As[row][vc * 8] = v;
      *(uint4*)&Bs[row][vc * 8] =
          *(const uint4*)&Web[(size_t)(col0 + row) * 256 + h * 128 + k0 + vc * 8];
    }
    __syncthreads();
    mfma_tile(As, Bs, acc, wm, wn, fr, fg);
    __syncthreads();
  }
#pragma unroll
  for (int mi = 0; mi < 4; mi++) {
#pragma unroll
    for (int rr = 0; rr < 4; rr++) {
      int grow = row0 + wm * 64 + mi * 16 + fg * 4 + rr;
      if (grow >= NND) continue;
#pragma unroll
      for (int ni = 0; ni < 4; ni++) {
        int gj = col0 + wn * 64 + ni * 16 + fr;
        qWeb[(size_t)grow * 512 + h * 256 + gj] = f2b(acc[mi][ni][rr]);
      }
    }
  }
}

// ---- fused per-node attention: single pass, online softmax, wave/node ----
__global__ __launch_bounds__(256) void node_fused(
    const u16* __restrict__ qb, const u16* __restrict__ kb,
    const u16* __restrict__ vb, const u16* __restrict__ qWeb,
    const int* __restrict__ ei, const float* __restrict__ last_update,
    const float* __restrict__ t, const float* __restrict__ msg,
    const float* __restrict__ tw, const float* __restrict__ tb_,
    const float* __restrict__ be, const float* __restrict__ u_edge,
    const float* __restrict__ u_attn, const int* __restrict__ rowptr,
    const int* __restrict__ elist, u16* __restrict__ aggb,
    float* __restrict__ out) {
  const int node = (blockIdx.x * blockDim.x + threadIdx.x) >> 6;
  const int lane = threadIdx.x & 63;
  if (node >= NND) return;
  const int beg = rowptr[node], end = rowptr[node + 1];
  const int c0 = lane * 4, hl = lane >> 5;

  // node-side loads (once)
  ushort4 q4 = *(const ushort4*)&qb[(size_t)node * 256 + c0];
  float qf0 = b2f(q4.x), qf1 = b2f(q4.y), qf2 = b2f(q4.z), qf3 = b2f(q4.w);
  ushort4 w0v = *(const ushort4*)&qWeb[(size_t)node * 512 + c0];
  ushort4 w1v = *(const ushort4*)&qWeb[(size_t)node * 512 + 256 + c0];
  float qw00 = b2f(w0v.x), qw01 = b2f(w0v.y), qw02 = b2f(w0v.z), qw03 = b2f(w0v.w);
  float qw10 = b2f(w1v.x), qw11 = b2f(w1v.y), qw12 = b2f(w1v.z), qw13 = b2f(w1v.w);
  float4 bev = *(const float4*)&be[c0];
  float pb = qf0 * bev.x + qf1 * bev.y + qf2 * bev.z + qf3 * bev.w;
#pragma unroll
  for (int off = 16; off; off >>= 1) pb += __shfl_xor(pb, off);  // per-head
  float tw0 = 0, tw1 = 0, tw2 = 0, tw3 = 0, tb0 = 0, tb1 = 0, tb2 = 0, tb3 = 0;
  if (c0 < 100) {
    float4 a = *(const float4*)&tw[c0];
    float4 b = *(const float4*)&tb_[c0];
    tw0 = a.x; tw1 = a.y; tw2 = a.z; tw3 = a.w;
    tb0 = b.x; tb1 = b.y; tb2 = b.z; tb3 = b.w;
  }
  const float inv = 0.08838834764831845f;  // 1/sqrt(128)

  // online-softmax state (per-head, redundant per lane)
  float m0 = -INFINITY, m1 = -INFINITY;
  float den0 = 0.f, den1 = 0.f, sw0 = 0.f, sw1 = 0.f;
  float vc0 = 0, vc1 = 0, vc2 = 0, vc3 = 0;
  float g00 = 0, g01 = 0, g02 = 0, g03 = 0;
  float g10 = 0, g11 = 0, g12 = 0, g13 = 0;

  for (int j = beg; j < end; ++j) {
    int eid = elist[j];
    int s = ei[eid];
    // independent loads — issue early, overlap with reductions
    float rt = last_update[s] - t[eid];
    ushort4 k4 = *(const ushort4*)&kb[(size_t)s * 256 + c0];
    ushort4 v4 = *(const ushort4*)&vb[(size_t)s * 256 + c0];
    bool keep = u_edge[eid] > PDROP;
    float2 ua = *(const float2*)&u_attn[(size_t)eid * 2];
    float ea0, ea1, ea2, ea3;
    if (c0 < 100) {
      ea0 = __cosf(rt * tw0 + tb0); ea1 = __cosf(rt * tw1 + tb1);
      ea2 = __cosf(rt * tw2 + tb2); ea3 = __cosf(rt * tw3 + tb3);
    } else {
      float4 mm = *(const float4*)&msg[(size_t)eid * 156 + (c0 - 100)];
      ea0 = mm.x; ea1 = mm.y; ea2 = mm.z; ea3 = mm.w;
    }
    float pqk = qf0 * b2f(k4.x) + qf1 * b2f(k4.y) + qf2 * b2f(k4.z) + qf3 * b2f(k4.w);
    float pe0 = qw00 * ea0 + qw01 * ea1 + qw02 * ea2 + qw03 * ea3;
    float pe1 = qw10 * ea0 + qw11 * ea1 + qw12 * ea2 + qw13 * ea3;
    float y0 = pe0 + __shfl_xor(pe0, 32);
    float y1 = pe1 + __shfl_xor(pe1, 32);
    float z = (lane < 32) ? y0 : y1;
#pragma unroll
    for (int off = 16; off; off >>= 1) {
      z += __shfl_xor(z, off);
      pqk += __shfl_xor(pqk, off);
    }
    float a = keep ? (pqk + z + pb) * inv : -INFINITY;
    float aoth = __shfl_xor(a, 32);
    float a0 = (lane < 32) ? a : aoth;
    float a1 = (lane < 32) ? aoth : a;
    // online rescale (wave-uniform branches)
    if (a0 > m0) {
      float sc = (m0 > -1e30f) ? __expf(m0 - a0) : 0.f;
      den0 *= sc; sw0 *= sc;
      g00 *= sc; g01 *= sc; g02 *= sc; g03 *= sc;
      float scv = hl ? 1.f : sc;
      vc0 *= scv; vc1 *= scv; vc2 *= scv; vc3 *= scv;
      m0 = a0;
    }
    if (a1 > m1) {
      float sc = (m1 > -1e30f) ? __expf(m1 - a1) : 0.f;
      den1 *= sc; sw1 *= sc;
      g10 *= sc; g11 *= sc; g12 *= sc; g13 *= sc;
      float scv = hl ? sc : 1.f;
      vc0 *= scv; vc1 *= scv; vc2 *= scv; vc3 *= scv;
      m1 = a1;
    }
    float ex0 = (a0 > -1e30f) ? __expf(a0 - m0) : 0.f;
    float ex1 = (a1 > -1e30f) ? __expf(a1 - m1) : 0.f;
    den0 += ex0; den1 += ex1;
    float w0 = ex0 * ((ua.x > PDROP) ? (1.f / 0.9f) : 0.f);
    float w1 = ex1 * ((ua.y > PDROP) ? (1.f / 0.9f) : 0.f);
    float wv = hl ? w1 : w0;
    vc0 += wv * b2f(v4.x); vc1 += wv * b2f(v4.y);
    vc2 += wv * b2f(v4.z); vc3 += wv * b2f(v4.w);
    g00 += w0 * ea0; g01 += w0 * ea1; g02 += w0 * ea2; g03 += w0 * ea3;
    g10 += w1 * ea0; g11 += w1 * ea1; g12 += w1 * ea2; g13 += w1 * ea3;
    sw0 += w0; sw1 += w1;
  }

  float rden0 = 1.f / (den0 + 1e-16f), rden1 = 1.f / (den1 + 1e-16f);
  float rv = hl ? rden1 : rden0;
  float swv = hl ? sw1 : sw0;
  float4 o = *(float4*)&out[(size_t)node * 256 + c0];
  o.x += (vc0 + swv * bev.x) * rv;
  o.y += (vc1 + swv * bev.y) * rv;
  o.z += (vc2 + swv * bev.z) * rv;
  o.w += (vc3 + swv * bev.w) * rv;
  *(float4*)&out[(size_t)node * 256 + c0] = o;
  ushort4 a0v, a1v;
  a0v.x = f2b(g00 * rden0); a0v.y = f2b(g01 * rden0);
  a0v.z = f2b(g02 * rden0); a0v.w = f2b(g03 * rden0);
  a1v.x = f2b(g10 * rden1); a1v.y = f2b(g11 * rden1);
  a1v.z = f2b(g12 * rden1); a1v.w = f2b(g13 * rden1);
  *(ushort4*)&aggb[(size_t)node * 256 + c0] = a0v;
  *(ushort4*)&aggb[(size_t)(NND + node) * 256 + c0] = a1v;
}

// ---- final GEMM: out[:, h*128 + c] += agg_h (Nx256) @ We_h (256x128) ----
__global__ __launch_bounds__(256) void gemm_final(const u16* __restrict__ aggb,
                                                  const u16* __restrict__ WeT,
                                                  float* __restrict__ out) {
  __shared__ __attribute__((aligned(16))) u16 As[128][72];
  __shared__ __attribute__((aligned(16))) u16 Bs[128][72];
  const int tid = threadIdx.x;
  const int h = blockIdx.y;
  const int row0 = blockIdx.x * 128;
  const u16* A = aggb + (size_t)h * NND * 256;
  const int wid = tid >> 6, lane = tid & 63;
  const int wm = wid >> 1, wn = wid & 1;
  const int fr = lane & 15, fg = lane >> 4;
  f32x4 acc[4][4] = {};
  for (int k0 = 0; k0 < 256; k0 += 64) {
#pragma unroll
    for (int i = 0; i < 4; i++) {
      int idx = tid + i * 256;
      int row = idx >> 3, vc = idx & 7;
      int g = row0 + row;
      uint4 v = make_uint4(0, 0, 0, 0);
      if (g < NND) v = *(const uint4*)&A[(size_t)g * 256 + k0 + vc * 8];
      *(uint4*)&As[row][vc * 8] = v;
      *(uint4*)&Bs[row][vc * 8] =
          *(const uint4*)&WeT[(size_t)(h * 128 + row) * 256 + k0 + vc * 8];
    }
    __syncthreads();
    mfma_tile(As, Bs, acc, wm, wn, fr, fg);
    __syncthreads();
  }
#pragma unroll
  for (int mi = 0; mi < 4; mi++) {
#pragma unroll
    for (int rr = 0; rr < 4; rr++) {
      int grow = row0 + wm * 64 + mi * 16 + fg * 4 + rr;
      if (grow >= NND) continue;
#pragma unroll
      for (int ni = 0; ni < 4; ni++) {
        int gcol = wn * 64 + ni * 16 + fr;
        out[(size_t)grow * 256 + h * 128 + gcol] += acc[mi][ni][rr];
      }
    }
  }
}

extern "C" void kernel_launch(void* const* d_in, const int* in_sizes, int n_in,
                              void* d_out, int out_size, void* d_ws, size_t ws_size,
                              hipStream_t stream) {
  const float* x = (const float*)d_in[0];
  const float* last_update = (const float*)d_in[1];
  const int* ei = (const int*)d_in[2];
  const float* t = (const float*)d_in[3];
  const float* msg = (const float*)d_in[4];
  const float* u_edge = (const float*)d_in[5];
  const float* u_attn = (const float*)d_in[6];
  const float* time_w = (const float*)d_in[7];
  const float* time_b = (const float*)d_in[8];
  const float* Wq = (const float*)d_in[9];
  const float* bq = (const float*)d_in[10];
  const float* Wk = (const float*)d_in[11];
  const float* bk = (const float*)d_in[12];
  const float* Wv = (const float*)d_in[13];
  const float* bv = (const float*)d_in[14];
  const float* We = (const float*)d_in[15];
  const float* be = (const float*)d_in[16];
  const float* Ws = (const float*)d_in[17];
  const float* bs = (const float*)d_in[18];
  float* out = (float*)d_out;

  char* ws = (char*)d_ws;
  u16* xb = (u16*)(ws + 0);                    // 10,240,000
  u16* WT0 = (u16*)(ws + 10240000);            // 786,432
  u16* qb = (u16*)(ws + 11026432);             // 10,240,000
  u16* kb = (u16*)(ws + 21266432);             // 10,240,000
  u16* vb = (u16*)(ws + 31506432);             // 10,240,000
  u16* qWeb = (u16*)(ws + 41746432);           // 20,480,000
  u16* aggb = (u16*)(ws + 62226432);           // 20,480,000
  int* cnt = (int*)(ws + 82706432);            // 80,000
  int* cur = (int*)(ws + 82786432);            // 80,000
  int* rowptr = (int*)(ws + 82866432);         // 80,004 (+pad)
  int* elist = (int*)(ws + 82946448);          // 800,000
  // total ~83.7 MB

  // CSR build
  zero2<<<(NND + 255) / 256, 256, 0, stream>>>(cnt, cur);
  csr_count<<<(NE + 255) / 256, 256, 0, stream>>>(ei, cnt);
  scan_rowptr<<<1, 1024, 0, stream>>>(cnt, rowptr);
  csr_fill<<<(NE + 255) / 256, 256, 0, stream>>>(ei, rowptr, cur, elist);

  // precompute
  WTArgs wa;
  wa.W[0] = Wq; wa.W[1] = Wk; wa.W[2] = Wv; wa.W[3] = Ws; wa.W[4] = We; wa.W[5] = We;
  for (int i = 0; i < 6; i++) wa.WT[i] = WT0 + (size_t)i * 65536;
  convert_wT<<<(6 * 65536 + 255) / 256, 256, 0, stream>>>(wa);
  convert_x<<<(NND * 64 + 255) / 256, 256, 0, stream>>>(x, xb);

  // node projections (q,k,v bf16; skip f32 -> out)
  NodeArgs na;
  na.BT[0] = wa.WT[0]; na.BT[1] = wa.WT[1]; na.BT[2] = wa.WT[2]; na.BT[3] = wa.WT[3];
  na.bias[0] = bq; na.bias[1] = bk; na.bias[2] = bv; na.bias[3] = bs;
  na.outb[0] = qb; na.outb[1] = kb; na.outb[2] = vb;
  na.outf = out;
  dim3 gn((NND + 127) / 128, 8);
  gemm_node<<<gn, 256, 0, stream>>>(xb, na);

  // qWe[n,h,256]
  dim3 gq((NND + 127) / 128, 4);
  gemm_qwe<<<gq, 256, 0, stream>>>(qb, wa.WT[5], qWeb);

  // fused single-pass attention per node
  node_fused<<<(NND + 3) / 4, 256, 0, stream>>>(
      qb, kb, vb, qWeb, ei, last_update, t, msg, time_w, time_b, be, u_edge,
      u_attn, rowptr, elist, aggb, out);

  // out += agg_h @ We_h
  dim3 gf((NND + 127) / 128, 2);
  gemm_final<<<gf, 256, 0, stream>>>(aggb, wa.WT[4], out);
}